// Round 18
// baseline (510.694 us; speedup 1.0000x reference)
//
#include <hip/hip_runtime.h>

#define N_NODES 50000
#define N_EDGES 400000
#define EP (N_EDGES + N_NODES)   // 450000 edges incl. self-loops
#define D 64
#define H 8
#define NEG_SLOPE 0.2f
#define LN_EPS 1e-5f
#define CHUNK 196
#define SCAN_BLOCKS 256
#define PAD_N 50048
#define GEMM_BLOCKS (782 * 8)    // PAD_N/64 x 8 col-quarters
#define LOG2E 1.4426950408889634f

typedef unsigned short ushort_t;
typedef unsigned int uint_t;
typedef unsigned char uchar_t;
typedef __attribute__((ext_vector_type(8))) short short8;
typedef __attribute__((ext_vector_type(4))) float f32x4;
typedef __attribute__((ext_vector_type(2))) float f32x2;

#if defined(__has_builtin)
#if __has_builtin(__builtin_amdgcn_cvt_pk_bf16_f32)
#define HAVE_CVT_PK_BF16 1
#endif
#endif

__device__ __forceinline__ ushort_t f2bf(float f) {
    uint_t u = __float_as_uint(f);
    u += 0x7fffu + ((u >> 16) & 1u);          // round-to-nearest-even
    return (ushort_t)(u >> 16);
}
__device__ __forceinline__ uint_t pack_bf2(float a, float b) {
#ifdef HAVE_CVT_PK_BF16
    typedef __attribute__((ext_vector_type(2))) __bf16 bf16x2_t;
    bf16x2_t v = __builtin_amdgcn_cvt_pk_bf16_f32(a, b);
    uint_t r;
    __builtin_memcpy(&r, &v, 4);
    return r;
#else
    return (uint_t)f2bf(a) | ((uint_t)f2bf(b) << 16);
#endif
}
__device__ __forceinline__ f32x2 mkf2(uint_t u) {
    f32x2 r;
    r.x = __uint_as_float(u << 16);
    r.y = __uint_as_float(u & 0xffff0000u);
    return r;
}
// fp8 e4m3 (OCP) pair -> f32x2 via HW converter; word-select must be an immediate -> template
template <bool HI>
__device__ __forceinline__ f32x2 cvt8(uint_t u) {
    typedef __attribute__((ext_vector_type(2))) float v2f;
    v2f r = __builtin_amdgcn_cvt_pk_f32_fp8((int)u, HI);
    return (f32x2){r.x, r.y};
}

// ---- forced packed-fp32 VALU ops ----
__device__ __forceinline__ f32x2 pk_add(f32x2 a, f32x2 b) {
    f32x2 d;
    asm("v_pk_add_f32 %0, %1, %2" : "=v"(d) : "v"(a), "v"(b));
    return d;
}
__device__ __forceinline__ f32x2 pk_mul(f32x2 a, f32x2 b) {
    f32x2 d;
    asm("v_pk_mul_f32 %0, %1, %2" : "=v"(d) : "v"(a), "v"(b));
    return d;
}
__device__ __forceinline__ f32x2 pk_fma(f32x2 a, f32x2 b, f32x2 c) {
    f32x2 d;
    asm("v_pk_fma_f32 %0, %1, %2, %3" : "=v"(d) : "v"(a), "v"(b), "v"(c));
    return d;
}
__device__ __forceinline__ f32x2 pk_abs(f32x2 a) {     // no v_pk_max_f32 on gfx950: 2x v_and_b32
    f32x2 r;
    r.x = __uint_as_float(__float_as_uint(a.x) & 0x7fffffffu);
    r.y = __uint_as_float(__float_as_uint(a.y) & 0x7fffffffu);
    return r;
}

// cross-lane reduce helpers
__device__ __forceinline__ float xor1_dpp(float x) {   // quad_perm [1,0,3,2]
    int i = __float_as_int(x);
    return __int_as_float(__builtin_amdgcn_update_dpp(i, i, 0xB1, 0xF, 0xF, 1));
}
__device__ __forceinline__ float xor2_dpp(float x) {   // quad_perm [2,3,0,1]
    int i = __float_as_int(x);
    return __int_as_float(__builtin_amdgcn_update_dpp(i, i, 0x4E, 0xF, 0xF, 1));
}
__device__ __forceinline__ float xor8_dpp(float x) {   // ROW_ROR:8 == lane^8 within 16-row
    int i = __float_as_int(x);
    return __int_as_float(__builtin_amdgcn_update_dpp(i, i, 0x128, 0xF, 0xF, 1));
}
__device__ __forceinline__ float xor4_swz(float x) {   // ds_swizzle xor 4
    return __int_as_float(__builtin_amdgcn_ds_swizzle(__float_as_int(x), 0x101F));
}
__device__ __forceinline__ float xor16_swz(float x) {  // ds_swizzle xor 16
    return __int_as_float(__builtin_amdgcn_ds_swizzle(__float_as_int(x), 0x401F));
}

// decode edge id -> (src, dst); ids >= N_EDGES are self-loops
__device__ __forceinline__ void edge_sd(const int* __restrict__ ei, int eid, int& s, int& d) {
    if (eid < N_EDGES) { s = ei[eid]; d = ei[N_EDGES + eid]; }
    else               { s = d = eid - N_EDGES; }
}

// device-scope barrier among NB co-resident blocks (counters zeroed by host memset each launch)
__device__ __forceinline__ void gbar(int* ctr, int nblk) {
    __syncthreads();
    if (threadIdx.x == 0) {
        __threadfence();                                  // release my writes (device scope)
        atomicAdd(ctr, 1);
        while (__hip_atomic_load(ctr, __ATOMIC_ACQUIRE, __HIP_MEMORY_SCOPE_AGENT) < nblk) {}
        __threadfence();                                  // acquire others' writes
    }
    __syncthreads();
}

// ---------------- fused setup: hist + bf16 conversions + all scans + degree sort (one kernel) ----------------
// 256 blocks (1/CU, co-residency guaranteed: 1024 waves << 8192 capacity), 3 internal barriers.
__global__ __launch_bounds__(256) void fused_setup(const int* __restrict__ ei, int* __restrict__ counts,
                                                   const float* __restrict__ x,
                                                   const float* __restrict__ Wl, const float* __restrict__ Wr,
                                                   ushort_t* __restrict__ xb, ushort_t* __restrict__ Wt,
                                                   int* __restrict__ bsum, int* __restrict__ bhist,
                                                   int* __restrict__ pbase, int* __restrict__ cursor,
                                                   int4* __restrict__ desc, int* __restrict__ bar) {
    int b = blockIdx.x, t = threadIdx.x;

    // ---- phase 1: edge histogram + x/W conversions (grid-stride) ----
    const int T1 = EP + N_NODES * 64 + 3 * 1024 * 64;
    for (int g = b * 256 + t; g < T1; g += SCAN_BLOCKS * 256) {
        int w = g;
        if (w < EP) {
            int s, d; edge_sd(ei, w, s, d);
            atomicAdd(&counts[d], 1);
            continue;
        }
        w -= EP;
        if (w < N_NODES * 64) { xb[w] = f2bf(x[w]); continue; }
        w -= N_NODES * 64;
        int l = w >> 16, rem = w & 65535, col = rem >> 6, k = rem & 63;
        float v = (col < 512) ? Wl[((size_t)l * 64 + k) * 512 + col]
                              : Wr[((size_t)l * 64 + k) * 512 + (col - 512)];
        Wt[w] = f2bf(v);
    }
    gbar(&bar[0], SCAN_BLOCKS);

    // ---- phase 2: per-chunk sum + degree histogram (scan1) ----
    {
        __shared__ int sd[256];
        __shared__ int hist[64];
        if (t < 64) hist[t] = 0;
        int idx = b * CHUNK + t;
        int v = (t < CHUNK && idx < N_NODES) ? counts[idx] : 0;
        sd[t] = v;
        __syncthreads();
        if (t < CHUNK && idx < N_NODES) atomicAdd(&hist[63 - min(v, 63)], 1);
        for (int d = 128; d > 0; d >>= 1) {
            __syncthreads();
            if (t < d) sd[t] += sd[t + d];
        }
        __syncthreads();
        if (t == 0) bsum[b] = sd[0];
        if (t < 64) bhist[b * 64 + t] = hist[t];
    }
    gbar(&bar[1], SCAN_BLOCKS);

    // ---- phase 3: block 0 does bsum exclusive scan + pbase (scan2) ----
    if (b == 0) {
        __shared__ int sd[256];
        __shared__ int sg[64 * 4];
        __shared__ int base[64];
        sd[t] = bsum[t];
        __syncthreads();
        for (int d = 1; d < 256; d <<= 1) {
            int v = (t >= d) ? sd[t - d] : 0;
            __syncthreads();
            if (t >= d) sd[t] += v;
            __syncthreads();
        }
        bsum[t] = (t > 0) ? sd[t - 1] : 0;

        int k = t & 63, g = t >> 6;
        int s = 0;
        for (int j = 0; j < 64; ++j) s += bhist[(g * 64 + j) * 64 + k];
        sg[k * 4 + g] = s;
        __syncthreads();
        if (t == 0) {
            int run = 0;
            for (int kk = 0; kk < 64; ++kk) {
                base[kk] = run;
                run += sg[kk * 4 + 0] + sg[kk * 4 + 1] + sg[kk * 4 + 2] + sg[kk * 4 + 3];
            }
        }
        __syncthreads();
        int run = base[k];
        for (int gg = 0; gg < g; ++gg) run += sg[k * 4 + gg];
        for (int j = 0; j < 64; ++j) {
            int bb = g * 64 + j;
            pbase[bb * 64 + k] = run;
            run += bhist[bb * 64 + k];
        }
    }
    gbar(&bar[2], SCAN_BLOCKS);

    // ---- phase 4: exclusive scan of counts -> cursor, desc placement (scan3) ----
    {
        __shared__ int sd[256];
        __shared__ int cur[64];
        if (t < 64) cur[t] = pbase[b * 64 + t];
        int idx = b * CHUNK + t;
        int v = (t < CHUNK && idx < N_NODES) ? counts[idx] : 0;
        sd[t] = v;
        __syncthreads();
        for (int d = 1; d < 256; d <<= 1) {
            int u = (t >= d) ? sd[t - d] : 0;
            __syncthreads();
            if (t >= d) sd[t] += u;
            __syncthreads();
        }
        if (t < CHUNK && idx < N_NODES) {
            int ex = bsum[b] + sd[t] - v;
            cursor[idx] = ex;
            int bin = 63 - min(v, 63);
            int p = atomicAdd(&cur[bin], 1);
            desc[p] = make_int4(idx, ex, ex + v, 0);
        }
    }
}

// ---------------- MFMA GEMM: x8[node][1024B] fp8 e4m3 (xl cols 0..511, xr cols 512..1023) ----------------
// LDS-staged epilogue: 2x coalesced 16B stores per thread (was 8x 4B: store-issue-bound).
__global__ __launch_bounds__(256) void gemm_mfma(const ushort_t* __restrict__ xb,
                                                 const ushort_t* __restrict__ Wt,
                                                 uchar_t* __restrict__ x8,
                                                 const int* __restrict__ ei, int* __restrict__ cursor,
                                                 int* __restrict__ csr_src) {
    __shared__ ushort_t sW[128 * 72];    // 128 cols x 64 k, rows padded to 72 shorts (18 KB)
    __shared__ uchar_t sOut[64 * 144];   // 64 nodes x 128B results, rows padded to 144B (9 KB)
    int b = blockIdx.x;
    if (b >= GEMM_BLOCKS) {              // scatter part (layer-0 launch only)
        int t = (b - GEMM_BLOCKS) * 256 + threadIdx.x;
        if (t >= EP) return;
        int s, d; edge_sd(ei, t, s, d);
        int pos = atomicAdd(&cursor[d], 1);
        csr_src[pos] = s;
        return;
    }
    int colq = b / 782;
    int bx = b - colq * 782;
    int t = threadIdx.x;
    const ushort_t* Wg = Wt + (size_t)colq * 128 * 64;
    {
        int col = t >> 1, half = t & 1;
        const uint4* g = (const uint4*)(Wg + col * 64 + half * 32);
        uint4* l = (uint4*)(sW + col * 72 + half * 32);
        l[0] = g[0]; l[1] = g[1]; l[2] = g[2]; l[3] = g[3];
    }
    __syncthreads();
    int lane = t & 63, w = t >> 6;
    int ln = lane & 15, q = lane >> 4;
    int nl = w * 16 + ln;                // node_local 0..63
    int node = bx * 64 + nl;
    int nclamp = node < N_NODES ? node : N_NODES - 1;
    const short8 b0 = *(const short8*)(xb + (size_t)nclamp * 64 + q * 8);
    const short8 b1 = *(const short8*)(xb + (size_t)nclamp * 64 + 32 + q * 8);
#pragma unroll
    for (int ct = 0; ct < 8; ++ct) {
        const short8 a0 = *(const short8*)(sW + (ct * 16 + ln) * 72 + q * 8);
        const short8 a1 = *(const short8*)(sW + (ct * 16 + ln) * 72 + 32 + q * 8);
        f32x4 acc = {0.f, 0.f, 0.f, 0.f};
        acc = __builtin_amdgcn_mfma_f32_16x16x32_bf16(a0, b0, acc, 0, 0, 0);
        acc = __builtin_amdgcn_mfma_f32_16x16x32_bf16(a1, b1, acc, 0, 0, 0);
        int r = 0;
        r = __builtin_amdgcn_cvt_pk_fp8_f32(acc[0], acc[1], r, false);
        r = __builtin_amdgcn_cvt_pk_fp8_f32(acc[2], acc[3], r, true);
        *(uint_t*)(sOut + nl * 144 + ct * 16 + q * 4) = (uint_t)r;   // LDS deposit (2-way alias max)
    }
    __syncthreads();
#pragma unroll
    for (int k = 0; k < 2; ++k) {
        int c = t + k * 256;
        int nl2 = c >> 3, off = (c & 7) * 16;
        int node2 = bx * 64 + nl2;
        if (node2 < N_NODES) {
            uint4 v = *(const uint4*)(sOut + nl2 * 144 + off);
            *(uint4*)(x8 + (size_t)node2 * 1024 + colq * 128 + off) = v;
        }
    }
}

// ---------------- fused node kernel: fp8 gathers, bf16 residual from xb (in-place) ----------------
__global__ __launch_bounds__(256, 8) void node_fused(ushort_t* __restrict__ xb,      // in: residual, out: next-layer input
                                                  const uchar_t* __restrict__ x8,
                                                  const float* __restrict__ att,
                                                  const int4* __restrict__ desc, const int* __restrict__ csr_src,
                                                  const float* __restrict__ bias, const float* __restrict__ gamma,
                                                  const float* __restrict__ beta, float* __restrict__ x_out,
                                                  int write_out, int write_xb) {
    int4 dd = desc[blockIdx.x * 4 + (threadIdx.x >> 6)];
    int n   = __builtin_amdgcn_readfirstlane(dd.x);
    int beg = __builtin_amdgcn_readfirstlane(dd.y);
    int end = __builtin_amdgcn_readfirstlane(dd.z);
    int lane = threadIdx.x & 63;
    int h = lane >> 3, i = lane & 7;
    int off8 = h * 64 + i * 8;   // byte offset into 512B half-row

    // loop-invariants: xr (fp8), attention vector (fp32)
    uint2 ru = *(const uint2*)(x8 + (size_t)n * 1024 + 512 + off8);
    f32x2 rv0 = cvt8<false>(ru.x), rv1 = cvt8<true>(ru.x),
          rv2 = cvt8<false>(ru.y), rv3 = cvt8<true>(ru.y);
    const float4* pa = (const float4*)(att + h * 64 + i * 8);
    float4 aa = pa[0], ab = pa[1];
    f32x2 a0 = {aa.x, aa.y}, a1 = {aa.z, aa.w}, a2 = {ab.x, ab.y}, a3 = {ab.z, ab.w};
    f32x2 a60 = (0.6f * LOG2E) * a0, a61 = (0.6f * LOG2E) * a1,
          a62 = (0.6f * LOG2E) * a2, a63 = (0.6f * LOG2E) * a3;
    f32x2 a40 = (0.4f * LOG2E) * a0, a41 = (0.4f * LOG2E) * a1,
          a42 = (0.4f * LOG2E) * a2, a43 = (0.4f * LOG2E) * a3;

    float den = 0.f;
    f32x2 acc0 = {0.f, 0.f}, acc1 = {0.f, 0.f}, acc2 = {0.f, 0.f}, acc3 = {0.f, 0.f};

#define PROCESS(cur)                                                     \
    {                                                                    \
        f32x2 v0 = cvt8<false>(cur.x), v1 = cvt8<true>(cur.x),           \
              v2 = cvt8<false>(cur.y), v3 = cvt8<true>(cur.y);           \
        f32x2 p = pk_mul(a60, v0);                                       \
        p = pk_fma(a61, v1, p);                                          \
        p = pk_fma(a62, v2, p);                                          \
        p = pk_fma(a63, v3, p);                                          \
        p = pk_fma(a40, pk_abs(pk_add(v0, rv0)), p);                     \
        p = pk_fma(a41, pk_abs(pk_add(v1, rv1)), p);                     \
        p = pk_fma(a42, pk_abs(pk_add(v2, rv2)), p);                     \
        p = pk_fma(a43, pk_abs(pk_add(v3, rv3)), p);                     \
        float pdot = p.x + p.y;                                          \
        pdot += xor1_dpp(pdot);                                          \
        pdot += xor2_dpp(pdot);                                          \
        pdot += xor4_swz(pdot);                                          \
        float wgt = __builtin_exp2f(pdot);                               \
        den += wgt;                                                      \
        f32x2 wv = {wgt, wgt};                                           \
        acc0 = pk_fma(wv, v0, acc0);                                     \
        acc1 = pk_fma(wv, v1, acc1);                                     \
        acc2 = pk_fma(wv, v2, acc2);                                     \
        acc3 = pk_fma(wv, v3, acc3);                                     \
    }

    for (int base = beg; base < end; base += 64) {
        int idx = base + lane;
        int srcs = csr_src[idx < end ? idx : end - 1];   // coalesced batch load
        int cnt = min(64, end - base);
        int j = 0;
        for (; j + 8 <= cnt; j += 8) {
            uint2 q[8];
#pragma unroll
            for (int u = 0; u < 8; ++u) {
                int ss = __shfl(srcs, j + u);
                q[u] = *(const uint2*)(x8 + (size_t)ss * 1024 + off8);
            }
#pragma unroll
            for (int u = 0; u < 8; ++u) PROCESS(q[u]);
        }
        for (; j < cnt; ++j) {
            int ss = __shfl(srcs, j);
            uint2 qq = *(const uint2*)(x8 + (size_t)ss * 1024 + off8);
            PROCESS(qq);
        }
    }
#undef PROCESS

    // normalize per head (0.125 head-mean folded in), reduce over heads (xor 8,16,32)
    float invden = 0.125f / den;
    f32x2 iv = {invden, invden};
    acc0 = pk_mul(acc0, iv); acc1 = pk_mul(acc1, iv);
    acc2 = pk_mul(acc2, iv); acc3 = pk_mul(acc3, iv);
    float acc[8] = {acc0.x, acc0.y, acc1.x, acc1.y, acc2.x, acc2.y, acc3.x, acc3.y};
#pragma unroll
    for (int k2 = 0; k2 < 8; ++k2) {
        acc[k2] += xor8_dpp(acc[k2]);
        acc[k2] += xor16_swz(acc[k2]);
        acc[k2] += __shfl_xor(acc[k2], 32);
    }

    // bias + residual (bf16 xb); LN stats across channels
    int cbase = i * 8;
    uint4 pxu = *(const uint4*)(xb + (size_t)n * 64 + cbase);
    f32x2 x01 = mkf2(pxu.x), x23 = mkf2(pxu.y), x45 = mkf2(pxu.z), x67 = mkf2(pxu.w);
    float xi[8] = {x01.x, x01.y, x23.x, x23.y, x45.x, x45.y, x67.x, x67.y};
    float v[8];
    float sum = 0.f, sq = 0.f;
#pragma unroll
    for (int k2 = 0; k2 < 8; ++k2) {
        float val = acc[k2] + bias[cbase + k2] + xi[k2];
        v[k2] = val; sum += val; sq += val * val;
    }
    sum += xor1_dpp(sum); sq += xor1_dpp(sq);
    sum += xor2_dpp(sum); sq += xor2_dpp(sq);
    sum += xor4_swz(sum); sq += xor4_swz(sq);
    float mu   = sum * (1.0f / 64.0f);
    float var  = sq * (1.0f / 64.0f) - mu * mu;
    float rstd = rsqrtf(var + LN_EPS);

    if (h == 0) {
        float o[8];
#pragma unroll
        for (int k2 = 0; k2 < 8; ++k2) {
            float y = (v[k2] - mu) * rstd * gamma[cbase + k2] + beta[cbase + k2];
            o[k2] = fmaxf(y, 0.f);
        }
        if (write_out) {
            float4* po = (float4*)(x_out + n * 64 + cbase);
            po[0] = make_float4(o[0], o[1], o[2], o[3]);
            po[1] = make_float4(o[4], o[5], o[6], o[7]);
        }
        if (write_xb) {
            *(uint4*)(xb + (size_t)n * 64 + cbase) =
                make_uint4(pack_bf2(o[0], o[1]), pack_bf2(o[2], o[3]),
                           pack_bf2(o[4], o[5]), pack_bf2(o[6], o[7]));
        }
    }
}

// ---------------- host ----------------

extern "C" void kernel_launch(void* const* d_in, const int* in_sizes, int n_in,
                              void* d_out, int out_size, void* d_ws, size_t ws_size,
                              hipStream_t stream) {
    const float* x     = (const float*)d_in[0];
    const float* Wl    = (const float*)d_in[1];
    const float* Wr    = (const float*)d_in[2];
    const float* att   = (const float*)d_in[3];
    const float* b     = (const float*)d_in[4];
    const float* gamma = (const float*)d_in[5];
    const float* beta  = (const float*)d_in[6];
    const int*   ei    = (const int*)d_in[7];
    float* out = (float*)d_out;

    uchar_t* x8    = (uchar_t*)d_ws;                         // PAD_N*1024 fp8 (xl | xr)
    ushort_t* xb   = (ushort_t*)(x8 + (size_t)PAD_N * 1024); // PAD_N*64 bf16 (layer input / residual)
    ushort_t* Wt   = xb + (size_t)PAD_N * 64;                // 3*1024*64 bf16
    int* counts    = (int*)(Wt + 3 * 1024 * 64);             // PAD_N
    int* bar       = counts + PAD_N;                         // 8 (barrier counters)
    int* cursor    = bar + 8;                                // PAD_N
    int* bsum      = cursor + PAD_N;                         // 256
    int* bhist     = bsum + 256;                             // 256*64
    int* pbase     = bhist + SCAN_BLOCKS * 64;               // 256*64
    int4* desc     = (int4*)(pbase + SCAN_BLOCKS * 64);      // PAD_N int4
    int* csr_src   = (int*)(desc + PAD_N);                   // EP

    // zero counts + barrier counters in one memset
    hipMemsetAsync(counts, 0, (PAD_N + 8) * sizeof(int), stream);

    // fused: histogram + bf16 conversions + scans + degree sort (1 kernel, 3 internal barriers)
    fused_setup<<<SCAN_BLOCKS, 256, 0, stream>>>(ei, counts, x, Wl, Wr, xb, Wt,
                                                 bsum, bhist, pbase, cursor, desc, bar);

    int eb = (EP + 255) / 256;
    for (int l = 0; l < 3; ++l) {
        int grid = (l == 0) ? GEMM_BLOCKS + eb : GEMM_BLOCKS;   // layer 0 also scatters CSR
        gemm_mfma <<<grid, 256, 0, stream>>>(xb, Wt + (size_t)l * 1024 * 64, x8, ei, cursor, csr_src);
        node_fused<<<N_NODES / 4, 256, 0, stream>>>(xb, x8, att + l * (H * D), desc, csr_src,
                                                    b + l * D, gamma + l * D, beta + l * D,
                                                    out, (l == 2) ? 1 : 0, (l < 2) ? 1 : 0);
    }
}

// Round 19
// 465.790 us; speedup vs baseline: 1.0964x; 1.0964x over previous
//
#include <hip/hip_runtime.h>

#define N_NODES 50000
#define N_EDGES 400000
#define EP (N_EDGES + N_NODES)   // 450000 edges incl. self-loops
#define D 64
#define H 8
#define NEG_SLOPE 0.2f
#define LN_EPS 1e-5f
#define CHUNK 196
#define SCAN_BLOCKS 256
#define PAD_N 50048
#define GEMM_BLOCKS (782 * 8)    // PAD_N/64 x 8 col-quarters
#define LOG2E 1.4426950408889634f

typedef unsigned short ushort_t;
typedef unsigned int uint_t;
typedef unsigned char uchar_t;
typedef __attribute__((ext_vector_type(8))) short short8;
typedef __attribute__((ext_vector_type(4))) float f32x4;
typedef __attribute__((ext_vector_type(2))) float f32x2;

#if defined(__has_builtin)
#if __has_builtin(__builtin_amdgcn_cvt_pk_bf16_f32)
#define HAVE_CVT_PK_BF16 1
#endif
#endif

__device__ __forceinline__ ushort_t f2bf(float f) {
    uint_t u = __float_as_uint(f);
    u += 0x7fffu + ((u >> 16) & 1u);          // round-to-nearest-even
    return (ushort_t)(u >> 16);
}
__device__ __forceinline__ uint_t pack_bf2(float a, float b) {
#ifdef HAVE_CVT_PK_BF16
    typedef __attribute__((ext_vector_type(2))) __bf16 bf16x2_t;
    bf16x2_t v = __builtin_amdgcn_cvt_pk_bf16_f32(a, b);
    uint_t r;
    __builtin_memcpy(&r, &v, 4);
    return r;
#else
    return (uint_t)f2bf(a) | ((uint_t)f2bf(b) << 16);
#endif
}
__device__ __forceinline__ f32x2 mkf2(uint_t u) {
    f32x2 r;
    r.x = __uint_as_float(u << 16);
    r.y = __uint_as_float(u & 0xffff0000u);
    return r;
}
// fp8 e4m3 (OCP) pair -> f32x2 via HW converter; word-select must be an immediate -> template
template <bool HI>
__device__ __forceinline__ f32x2 cvt8(uint_t u) {
    typedef __attribute__((ext_vector_type(2))) float v2f;
    v2f r = __builtin_amdgcn_cvt_pk_f32_fp8((int)u, HI);
    return (f32x2){r.x, r.y};
}

// ---- forced packed-fp32 VALU ops ----
__device__ __forceinline__ f32x2 pk_add(f32x2 a, f32x2 b) {
    f32x2 d;
    asm("v_pk_add_f32 %0, %1, %2" : "=v"(d) : "v"(a), "v"(b));
    return d;
}
__device__ __forceinline__ f32x2 pk_mul(f32x2 a, f32x2 b) {
    f32x2 d;
    asm("v_pk_mul_f32 %0, %1, %2" : "=v"(d) : "v"(a), "v"(b));
    return d;
}
__device__ __forceinline__ f32x2 pk_fma(f32x2 a, f32x2 b, f32x2 c) {
    f32x2 d;
    asm("v_pk_fma_f32 %0, %1, %2, %3" : "=v"(d) : "v"(a), "v"(b), "v"(c));
    return d;
}
__device__ __forceinline__ f32x2 pk_abs(f32x2 a) {     // no v_pk_max_f32 on gfx950: 2x v_and_b32
    f32x2 r;
    r.x = __uint_as_float(__float_as_uint(a.x) & 0x7fffffffu);
    r.y = __uint_as_float(__float_as_uint(a.y) & 0x7fffffffu);
    return r;
}

// cross-lane reduce helpers
__device__ __forceinline__ float xor1_dpp(float x) {   // quad_perm [1,0,3,2]
    int i = __float_as_int(x);
    return __int_as_float(__builtin_amdgcn_update_dpp(i, i, 0xB1, 0xF, 0xF, 1));
}
__device__ __forceinline__ float xor2_dpp(float x) {   // quad_perm [2,3,0,1]
    int i = __float_as_int(x);
    return __int_as_float(__builtin_amdgcn_update_dpp(i, i, 0x4E, 0xF, 0xF, 1));
}
__device__ __forceinline__ float xor8_dpp(float x) {   // ROW_ROR:8 == lane^8 within 16-row
    int i = __float_as_int(x);
    return __int_as_float(__builtin_amdgcn_update_dpp(i, i, 0x128, 0xF, 0xF, 1));
}
__device__ __forceinline__ float xor4_swz(float x) {   // ds_swizzle xor 4
    return __int_as_float(__builtin_amdgcn_ds_swizzle(__float_as_int(x), 0x101F));
}
__device__ __forceinline__ float xor16_swz(float x) {  // ds_swizzle xor 16
    return __int_as_float(__builtin_amdgcn_ds_swizzle(__float_as_int(x), 0x401F));
}

// decode edge id -> (src, dst); ids >= N_EDGES are self-loops
__device__ __forceinline__ void edge_sd(const int* __restrict__ ei, int eid, int& s, int& d) {
    if (eid < N_EDGES) { s = ei[eid]; d = ei[N_EDGES + eid]; }
    else               { s = d = eid - N_EDGES; }
}

// device-scope barrier among NB co-resident blocks (counters zeroed by host memset each launch)
__device__ __forceinline__ void gbar(int* ctr, int nblk) {
    __syncthreads();
    if (threadIdx.x == 0) {
        __threadfence();
        atomicAdd(ctr, 1);
        while (__hip_atomic_load(ctr, __ATOMIC_ACQUIRE, __HIP_MEMORY_SCOPE_AGENT) < nblk) {}
        __threadfence();
    }
    __syncthreads();
}

// ---------------- setup: edge histogram + bf16 conversions (WIDE launch — R18 lesson:
// memory-bound bulk work must never sit behind a co-residency-capped grid) ----------------
__global__ __launch_bounds__(256) void setup_all(const int* __restrict__ ei, int* __restrict__ counts,
                                                 const float* __restrict__ x,
                                                 const float* __restrict__ Wl, const float* __restrict__ Wr,
                                                 ushort_t* __restrict__ xb, ushort_t* __restrict__ Wt) {
    int t = blockIdx.x * 256 + threadIdx.x;
    if (t < EP) {
        int s, d; edge_sd(ei, t, s, d);
        atomicAdd(&counts[d], 1);
        return;
    }
    t -= EP;
    if (t < N_NODES * 64) { xb[t] = f2bf(x[t]); return; }
    t -= N_NODES * 64;
    if (t >= 3 * 1024 * 64) return;
    int l = t >> 16, rem = t & 65535, col = rem >> 6, k = rem & 63;
    float v = (col < 512) ? Wl[((size_t)l * 64 + k) * 512 + col]
                          : Wr[((size_t)l * 64 + k) * 512 + (col - 512)];
    Wt[t] = f2bf(v);
}

// ---------------- fused CSR scans (small work, 256 blocks, 2 internal barriers) ----------------
__global__ __launch_bounds__(256) void csr_scans(const int* __restrict__ counts, int* __restrict__ bsum,
                                                 int* __restrict__ bhist, int* __restrict__ pbase,
                                                 int* __restrict__ cursor, int4* __restrict__ desc,
                                                 int* __restrict__ bar) {
    int b = blockIdx.x, t = threadIdx.x;
    __shared__ int sd[256];
    __shared__ int aux[256];   // hist / sg+base reuse

    // ---- phase 1 (scan1): per-chunk sum + degree histogram ----
    {
        if (t < 64) aux[t] = 0;
        int idx = b * CHUNK + t;
        int v = (t < CHUNK && idx < N_NODES) ? counts[idx] : 0;
        sd[t] = v;
        __syncthreads();
        if (t < CHUNK && idx < N_NODES) atomicAdd(&aux[63 - min(v, 63)], 1);
        for (int d = 128; d > 0; d >>= 1) {
            __syncthreads();
            if (t < d) sd[t] += sd[t + d];
        }
        __syncthreads();
        if (t == 0) bsum[b] = sd[0];
        if (t < 64) bhist[b * 64 + t] = aux[t];
    }
    gbar(&bar[0], SCAN_BLOCKS);

    // ---- phase 2 (scan2): block 0 — bsum exclusive scan + pbase ----
    if (b == 0) {
        __shared__ int sg[64 * 4];
        __shared__ int base[64];
        sd[t] = bsum[t];
        __syncthreads();
        for (int d = 1; d < 256; d <<= 1) {
            int v = (t >= d) ? sd[t - d] : 0;
            __syncthreads();
            if (t >= d) sd[t] += v;
            __syncthreads();
        }
        bsum[t] = (t > 0) ? sd[t - 1] : 0;

        int k = t & 63, g = t >> 6;
        int s = 0;
        for (int j = 0; j < 64; ++j) s += bhist[(g * 64 + j) * 64 + k];
        sg[k * 4 + g] = s;
        __syncthreads();
        if (t == 0) {
            int run = 0;
            for (int kk = 0; kk < 64; ++kk) {
                base[kk] = run;
                run += sg[kk * 4 + 0] + sg[kk * 4 + 1] + sg[kk * 4 + 2] + sg[kk * 4 + 3];
            }
        }
        __syncthreads();
        int run = base[k];
        for (int gg = 0; gg < g; ++gg) run += sg[k * 4 + gg];
        for (int j = 0; j < 64; ++j) {
            int bb = g * 64 + j;
            pbase[bb * 64 + k] = run;
            run += bhist[bb * 64 + k];
        }
    }
    gbar(&bar[1], SCAN_BLOCKS);

    // ---- phase 3 (scan3): exclusive scan of counts -> cursor + desc placement ----
    {
        if (t < 64) aux[t] = pbase[b * 64 + t];
        int idx = b * CHUNK + t;
        int v = (t < CHUNK && idx < N_NODES) ? counts[idx] : 0;
        sd[t] = v;
        __syncthreads();
        for (int d = 1; d < 256; d <<= 1) {
            int u = (t >= d) ? sd[t - d] : 0;
            __syncthreads();
            if (t >= d) sd[t] += u;
            __syncthreads();
        }
        if (t < CHUNK && idx < N_NODES) {
            int ex = bsum[b] + sd[t] - v;
            cursor[idx] = ex;
            int bin = 63 - min(v, 63);
            int p = atomicAdd(&aux[bin], 1);
            desc[p] = make_int4(idx, ex, ex + v, 0);
        }
    }
}

// ---------------- MFMA GEMM: x8[node][1024B] fp8 e4m3 (xl cols 0..511, xr cols 512..1023) ----------------
// LDS-staged epilogue: 2x coalesced 16B stores per thread (was 8x 4B: store-issue-bound).
__global__ __launch_bounds__(256) void gemm_mfma(const ushort_t* __restrict__ xb,
                                                 const ushort_t* __restrict__ Wt,
                                                 uchar_t* __restrict__ x8,
                                                 const int* __restrict__ ei, int* __restrict__ cursor,
                                                 int* __restrict__ csr_src) {
    __shared__ ushort_t sW[128 * 72];    // 128 cols x 64 k, rows padded to 72 shorts (18 KB)
    __shared__ uchar_t sOut[64 * 144];   // 64 nodes x 128B results, rows padded to 144B (9 KB)
    int b = blockIdx.x;
    if (b >= GEMM_BLOCKS) {              // scatter part (layer-0 launch only)
        int t = (b - GEMM_BLOCKS) * 256 + threadIdx.x;
        if (t >= EP) return;
        int s, d; edge_sd(ei, t, s, d);
        int pos = atomicAdd(&cursor[d], 1);
        csr_src[pos] = s;
        return;
    }
    int colq = b / 782;
    int bx = b - colq * 782;
    int t = threadIdx.x;
    const ushort_t* Wg = Wt + (size_t)colq * 128 * 64;
    {
        int col = t >> 1, half = t & 1;
        const uint4* g = (const uint4*)(Wg + col * 64 + half * 32);
        uint4* l = (uint4*)(sW + col * 72 + half * 32);
        l[0] = g[0]; l[1] = g[1]; l[2] = g[2]; l[3] = g[3];
    }
    __syncthreads();
    int lane = t & 63, w = t >> 6;
    int ln = lane & 15, q = lane >> 4;
    int nl = w * 16 + ln;                // node_local 0..63
    int node = bx * 64 + nl;
    int nclamp = node < N_NODES ? node : N_NODES - 1;
    const short8 b0 = *(const short8*)(xb + (size_t)nclamp * 64 + q * 8);
    const short8 b1 = *(const short8*)(xb + (size_t)nclamp * 64 + 32 + q * 8);
#pragma unroll
    for (int ct = 0; ct < 8; ++ct) {
        const short8 a0 = *(const short8*)(sW + (ct * 16 + ln) * 72 + q * 8);
        const short8 a1 = *(const short8*)(sW + (ct * 16 + ln) * 72 + 32 + q * 8);
        f32x4 acc = {0.f, 0.f, 0.f, 0.f};
        acc = __builtin_amdgcn_mfma_f32_16x16x32_bf16(a0, b0, acc, 0, 0, 0);
        acc = __builtin_amdgcn_mfma_f32_16x16x32_bf16(a1, b1, acc, 0, 0, 0);
        int r = 0;
        r = __builtin_amdgcn_cvt_pk_fp8_f32(acc[0], acc[1], r, false);
        r = __builtin_amdgcn_cvt_pk_fp8_f32(acc[2], acc[3], r, true);
        *(uint_t*)(sOut + nl * 144 + ct * 16 + q * 4) = (uint_t)r;   // LDS deposit (2-way alias max)
    }
    __syncthreads();
#pragma unroll
    for (int k = 0; k < 2; ++k) {
        int c = t + k * 256;
        int nl2 = c >> 3, off = (c & 7) * 16;
        int node2 = bx * 64 + nl2;
        if (node2 < N_NODES) {
            uint4 v = *(const uint4*)(sOut + nl2 * 144 + off);
            *(uint4*)(x8 + (size_t)node2 * 1024 + colq * 128 + off) = v;
        }
    }
}

// ---------------- fused node kernel: fp8 gathers, bf16 residual from xb (in-place) ----------------
__global__ __launch_bounds__(256, 8) void node_fused(ushort_t* __restrict__ xb,      // in: residual, out: next-layer input
                                                  const uchar_t* __restrict__ x8,
                                                  const float* __restrict__ att,
                                                  const int4* __restrict__ desc, const int* __restrict__ csr_src,
                                                  const float* __restrict__ bias, const float* __restrict__ gamma,
                                                  const float* __restrict__ beta, float* __restrict__ x_out,
                                                  int write_out, int write_xb) {
    int4 dd = desc[blockIdx.x * 4 + (threadIdx.x >> 6)];
    int n   = __builtin_amdgcn_readfirstlane(dd.x);
    int beg = __builtin_amdgcn_readfirstlane(dd.y);
    int end = __builtin_amdgcn_readfirstlane(dd.z);
    int lane = threadIdx.x & 63;
    int h = lane >> 3, i = lane & 7;
    int off8 = h * 64 + i * 8;   // byte offset into 512B half-row

    // loop-invariants: xr (fp8), attention vector (fp32)
    uint2 ru = *(const uint2*)(x8 + (size_t)n * 1024 + 512 + off8);
    f32x2 rv0 = cvt8<false>(ru.x), rv1 = cvt8<true>(ru.x),
          rv2 = cvt8<false>(ru.y), rv3 = cvt8<true>(ru.y);
    const float4* pa = (const float4*)(att + h * 64 + i * 8);
    float4 aa = pa[0], ab = pa[1];
    f32x2 a0 = {aa.x, aa.y}, a1 = {aa.z, aa.w}, a2 = {ab.x, ab.y}, a3 = {ab.z, ab.w};
    f32x2 a60 = (0.6f * LOG2E) * a0, a61 = (0.6f * LOG2E) * a1,
          a62 = (0.6f * LOG2E) * a2, a63 = (0.6f * LOG2E) * a3;
    f32x2 a40 = (0.4f * LOG2E) * a0, a41 = (0.4f * LOG2E) * a1,
          a42 = (0.4f * LOG2E) * a2, a43 = (0.4f * LOG2E) * a3;

    float den = 0.f;
    f32x2 acc0 = {0.f, 0.f}, acc1 = {0.f, 0.f}, acc2 = {0.f, 0.f}, acc3 = {0.f, 0.f};

#define PROCESS(cur)                                                     \
    {                                                                    \
        f32x2 v0 = cvt8<false>(cur.x), v1 = cvt8<true>(cur.x),           \
              v2 = cvt8<false>(cur.y), v3 = cvt8<true>(cur.y);           \
        f32x2 p = pk_mul(a60, v0);                                       \
        p = pk_fma(a61, v1, p);                                          \
        p = pk_fma(a62, v2, p);                                          \
        p = pk_fma(a63, v3, p);                                          \
        p = pk_fma(a40, pk_abs(pk_add(v0, rv0)), p);                     \
        p = pk_fma(a41, pk_abs(pk_add(v1, rv1)), p);                     \
        p = pk_fma(a42, pk_abs(pk_add(v2, rv2)), p);                     \
        p = pk_fma(a43, pk_abs(pk_add(v3, rv3)), p);                     \
        float pdot = p.x + p.y;                                          \
        pdot += xor1_dpp(pdot);                                          \
        pdot += xor2_dpp(pdot);                                          \
        pdot += xor4_swz(pdot);                                          \
        float wgt = __builtin_exp2f(pdot);                               \
        den += wgt;                                                      \
        f32x2 wv = {wgt, wgt};                                           \
        acc0 = pk_fma(wv, v0, acc0);                                     \
        acc1 = pk_fma(wv, v1, acc1);                                     \
        acc2 = pk_fma(wv, v2, acc2);                                     \
        acc3 = pk_fma(wv, v3, acc3);                                     \
    }

    for (int base = beg; base < end; base += 64) {
        int idx = base + lane;
        int srcs = csr_src[idx < end ? idx : end - 1];   // coalesced batch load
        int cnt = min(64, end - base);
        int j = 0;
        for (; j + 8 <= cnt; j += 8) {
            uint2 q[8];
#pragma unroll
            for (int u = 0; u < 8; ++u) {
                int ss = __shfl(srcs, j + u);
                q[u] = *(const uint2*)(x8 + (size_t)ss * 1024 + off8);
            }
#pragma unroll
            for (int u = 0; u < 8; ++u) PROCESS(q[u]);
        }
        for (; j < cnt; ++j) {
            int ss = __shfl(srcs, j);
            uint2 qq = *(const uint2*)(x8 + (size_t)ss * 1024 + off8);
            PROCESS(qq);
        }
    }
#undef PROCESS

    // normalize per head (0.125 head-mean folded in), reduce over heads (xor 8,16,32)
    float invden = 0.125f / den;
    f32x2 iv = {invden, invden};
    acc0 = pk_mul(acc0, iv); acc1 = pk_mul(acc1, iv);
    acc2 = pk_mul(acc2, iv); acc3 = pk_mul(acc3, iv);
    float acc[8] = {acc0.x, acc0.y, acc1.x, acc1.y, acc2.x, acc2.y, acc3.x, acc3.y};
#pragma unroll
    for (int k2 = 0; k2 < 8; ++k2) {
        acc[k2] += xor8_dpp(acc[k2]);
        acc[k2] += xor16_swz(acc[k2]);
        acc[k2] += __shfl_xor(acc[k2], 32);
    }

    // bias + residual (bf16 xb); LN stats across channels
    int cbase = i * 8;
    uint4 pxu = *(const uint4*)(xb + (size_t)n * 64 + cbase);
    f32x2 x01 = mkf2(pxu.x), x23 = mkf2(pxu.y), x45 = mkf2(pxu.z), x67 = mkf2(pxu.w);
    float xi[8] = {x01.x, x01.y, x23.x, x23.y, x45.x, x45.y, x67.x, x67.y};
    float v[8];
    float sum = 0.f, sq = 0.f;
#pragma unroll
    for (int k2 = 0; k2 < 8; ++k2) {
        float val = acc[k2] + bias[cbase + k2] + xi[k2];
        v[k2] = val; sum += val; sq += val * val;
    }
    sum += xor1_dpp(sum); sq += xor1_dpp(sq);
    sum += xor2_dpp(sum); sq += xor2_dpp(sq);
    sum += xor4_swz(sum); sq += xor4_swz(sq);
    float mu   = sum * (1.0f / 64.0f);
    float var  = sq * (1.0f / 64.0f) - mu * mu;
    float rstd = rsqrtf(var + LN_EPS);

    if (h == 0) {
        float o[8];
#pragma unroll
        for (int k2 = 0; k2 < 8; ++k2) {
            float y = (v[k2] - mu) * rstd * gamma[cbase + k2] + beta[cbase + k2];
            o[k2] = fmaxf(y, 0.f);
        }
        if (write_out) {
            float4* po = (float4*)(x_out + n * 64 + cbase);
            po[0] = make_float4(o[0], o[1], o[2], o[3]);
            po[1] = make_float4(o[4], o[5], o[6], o[7]);
        }
        if (write_xb) {
            *(uint4*)(xb + (size_t)n * 64 + cbase) =
                make_uint4(pack_bf2(o[0], o[1]), pack_bf2(o[2], o[3]),
                           pack_bf2(o[4], o[5]), pack_bf2(o[6], o[7]));
        }
    }
}

// ---------------- host ----------------

extern "C" void kernel_launch(void* const* d_in, const int* in_sizes, int n_in,
                              void* d_out, int out_size, void* d_ws, size_t ws_size,
                              hipStream_t stream) {
    const float* x     = (const float*)d_in[0];
    const float* Wl    = (const float*)d_in[1];
    const float* Wr    = (const float*)d_in[2];
    const float* att   = (const float*)d_in[3];
    const float* b     = (const float*)d_in[4];
    const float* gamma = (const float*)d_in[5];
    const float* beta  = (const float*)d_in[6];
    const int*   ei    = (const int*)d_in[7];
    float* out = (float*)d_out;

    uchar_t* x8    = (uchar_t*)d_ws;                         // PAD_N*1024 fp8 (xl | xr)
    ushort_t* xb   = (ushort_t*)(x8 + (size_t)PAD_N * 1024); // PAD_N*64 bf16 (layer input / residual)
    ushort_t* Wt   = xb + (size_t)PAD_N * 64;                // 3*1024*64 bf16
    int* counts    = (int*)(Wt + 3 * 1024 * 64);             // PAD_N
    int* bar       = counts + PAD_N;                         // 8 (barrier counters)
    int* cursor    = bar + 8;                                // PAD_N
    int* bsum      = cursor + PAD_N;                         // 256
    int* bhist     = bsum + 256;                             // 256*64
    int* pbase     = bhist + SCAN_BLOCKS * 64;               // 256*64
    int4* desc     = (int4*)(pbase + SCAN_BLOCKS * 64);      // PAD_N int4
    int* csr_src   = (int*)(desc + PAD_N);                   // EP

    // zero counts + barrier counters in one memset
    hipMemsetAsync(counts, 0, (PAD_N + 8) * sizeof(int), stream);

    // wide setup: histogram + bf16 conversions
    int setup_threads = EP + N_NODES * 64 + 3 * 1024 * 64;
    setup_all<<<(setup_threads + 255) / 256, 256, 0, stream>>>(ei, counts, x, Wl, Wr, xb, Wt);

    // fused scans (small work, 256 blocks, 2 internal device barriers)
    csr_scans<<<SCAN_BLOCKS, 256, 0, stream>>>(counts, bsum, bhist, pbase, cursor, desc, bar);

    int eb = (EP + 255) / 256;
    for (int l = 0; l < 3; ++l) {
        int grid = (l == 0) ? GEMM_BLOCKS + eb : GEMM_BLOCKS;   // layer 0 also scatters CSR
        gemm_mfma <<<grid, 256, 0, stream>>>(xb, Wt + (size_t)l * 1024 * 64, x8, ei, cursor, csr_src);
        node_fused<<<N_NODES / 4, 256, 0, stream>>>(xb, x8, att + l * (H * D), desc, csr_src,
                                                    b + l * D, gamma + l * D, beta + l * D,
                                                    out, (l == 2) ? 1 : 0, (l < 2) ? 1 : 0);
    }
}

// Round 20
// 384.908 us; speedup vs baseline: 1.3268x; 1.2101x over previous
//
#include <hip/hip_runtime.h>

#define N_NODES 50000
#define N_EDGES 400000
#define EP (N_EDGES + N_NODES)   // 450000 edges incl. self-loops
#define D 64
#define H 8
#define NEG_SLOPE 0.2f
#define LN_EPS 1e-5f
#define CHUNK 196
#define SCAN_BLOCKS 256
#define PAD_N 50048
#define GEMM_BLOCKS (782 * 8)    // PAD_N/64 x 8 col-quarters
#define LOG2E 1.4426950408889634f

typedef unsigned short ushort_t;
typedef unsigned int uint_t;
typedef unsigned char uchar_t;
typedef __attribute__((ext_vector_type(8))) short short8;
typedef __attribute__((ext_vector_type(4))) float f32x4;
typedef __attribute__((ext_vector_type(2))) float f32x2;

#if defined(__has_builtin)
#if __has_builtin(__builtin_amdgcn_cvt_pk_bf16_f32)
#define HAVE_CVT_PK_BF16 1
#endif
#endif

// R18/R19 lessons (measured):
//  - device-scope spin barriers cost ~50 us each on MI355X -> never trade a ~3 us
//    kernel-launch boundary for a software grid barrier.
//  - memory-bound bulk work must not sit behind a co-residency-capped grid.
// This file is the R17 configuration (session best, 385 us), restored verbatim.

__device__ __forceinline__ ushort_t f2bf(float f) {
    uint_t u = __float_as_uint(f);
    u += 0x7fffu + ((u >> 16) & 1u);          // round-to-nearest-even
    return (ushort_t)(u >> 16);
}
__device__ __forceinline__ uint_t pack_bf2(float a, float b) {
#ifdef HAVE_CVT_PK_BF16
    typedef __attribute__((ext_vector_type(2))) __bf16 bf16x2_t;
    bf16x2_t v = __builtin_amdgcn_cvt_pk_bf16_f32(a, b);
    uint_t r;
    __builtin_memcpy(&r, &v, 4);
    return r;
#else
    return (uint_t)f2bf(a) | ((uint_t)f2bf(b) << 16);
#endif
}
__device__ __forceinline__ f32x2 mkf2(uint_t u) {
    f32x2 r;
    r.x = __uint_as_float(u << 16);
    r.y = __uint_as_float(u & 0xffff0000u);
    return r;
}
// fp8 e4m3 (OCP) pair -> f32x2 via HW converter; word-select must be an immediate -> template
template <bool HI>
__device__ __forceinline__ f32x2 cvt8(uint_t u) {
    typedef __attribute__((ext_vector_type(2))) float v2f;
    v2f r = __builtin_amdgcn_cvt_pk_f32_fp8((int)u, HI);
    return (f32x2){r.x, r.y};
}

// ---- forced packed-fp32 VALU ops ----
__device__ __forceinline__ f32x2 pk_add(f32x2 a, f32x2 b) {
    f32x2 d;
    asm("v_pk_add_f32 %0, %1, %2" : "=v"(d) : "v"(a), "v"(b));
    return d;
}
__device__ __forceinline__ f32x2 pk_mul(f32x2 a, f32x2 b) {
    f32x2 d;
    asm("v_pk_mul_f32 %0, %1, %2" : "=v"(d) : "v"(a), "v"(b));
    return d;
}
__device__ __forceinline__ f32x2 pk_fma(f32x2 a, f32x2 b, f32x2 c) {
    f32x2 d;
    asm("v_pk_fma_f32 %0, %1, %2, %3" : "=v"(d) : "v"(a), "v"(b), "v"(c));
    return d;
}
__device__ __forceinline__ f32x2 pk_abs(f32x2 a) {     // no v_pk_max_f32 on gfx950: 2x v_and_b32
    f32x2 r;
    r.x = __uint_as_float(__float_as_uint(a.x) & 0x7fffffffu);
    r.y = __uint_as_float(__float_as_uint(a.y) & 0x7fffffffu);
    return r;
}

// cross-lane reduce helpers
__device__ __forceinline__ float xor1_dpp(float x) {   // quad_perm [1,0,3,2]
    int i = __float_as_int(x);
    return __int_as_float(__builtin_amdgcn_update_dpp(i, i, 0xB1, 0xF, 0xF, 1));
}
__device__ __forceinline__ float xor2_dpp(float x) {   // quad_perm [2,3,0,1]
    int i = __float_as_int(x);
    return __int_as_float(__builtin_amdgcn_update_dpp(i, i, 0x4E, 0xF, 0xF, 1));
}
__device__ __forceinline__ float xor8_dpp(float x) {   // ROW_ROR:8 == lane^8 within 16-row
    int i = __float_as_int(x);
    return __int_as_float(__builtin_amdgcn_update_dpp(i, i, 0x128, 0xF, 0xF, 1));
}
__device__ __forceinline__ float xor4_swz(float x) {   // ds_swizzle xor 4
    return __int_as_float(__builtin_amdgcn_ds_swizzle(__float_as_int(x), 0x101F));
}
__device__ __forceinline__ float xor16_swz(float x) {  // ds_swizzle xor 16
    return __int_as_float(__builtin_amdgcn_ds_swizzle(__float_as_int(x), 0x401F));
}

// decode edge id -> (src, dst); ids >= N_EDGES are self-loops
__device__ __forceinline__ void edge_sd(const int* __restrict__ ei, int eid, int& s, int& d) {
    if (eid < N_EDGES) { s = ei[eid]; d = ei[N_EDGES + eid]; }
    else               { s = d = eid - N_EDGES; }
}

// ---------------- setup: edge histogram + bf16 conversions ----------------

__global__ __launch_bounds__(256) void setup_all(const int* __restrict__ ei, int* __restrict__ counts,
                                                 const float* __restrict__ x,
                                                 const float* __restrict__ Wl, const float* __restrict__ Wr,
                                                 ushort_t* __restrict__ xb, ushort_t* __restrict__ Wt) {
    int t = blockIdx.x * 256 + threadIdx.x;
    if (t < EP) {
        int s, d; edge_sd(ei, t, s, d);
        atomicAdd(&counts[d], 1);
        return;
    }
    t -= EP;
    if (t < N_NODES * 64) { xb[t] = f2bf(x[t]); return; }
    t -= N_NODES * 64;
    if (t >= 3 * 1024 * 64) return;
    int l = t >> 16, rem = t & 65535, col = rem >> 6, k = rem & 63;
    float v = (col < 512) ? Wl[((size_t)l * 64 + k) * 512 + col]
                          : Wr[((size_t)l * 64 + k) * 512 + (col - 512)];
    Wt[t] = f2bf(v);
}

// ---------------- CSR scans + degree sort (three small kernels; boundaries are the sync) ----------------

__global__ __launch_bounds__(256) void csr_scan1(const int* __restrict__ counts, int* __restrict__ bsum,
                                                 int* __restrict__ bhist) {
    __shared__ int sd[256];
    __shared__ int hist[64];
    int t = threadIdx.x, b = blockIdx.x;
    if (t < 64) hist[t] = 0;
    int idx = b * CHUNK + t;
    int v = (t < CHUNK && idx < N_NODES) ? counts[idx] : 0;
    sd[t] = v;
    __syncthreads();
    if (t < CHUNK && idx < N_NODES) atomicAdd(&hist[63 - min(v, 63)], 1);
    for (int d = 128; d > 0; d >>= 1) {
        __syncthreads();
        if (t < d) sd[t] += sd[t + d];
    }
    __syncthreads();
    if (t == 0) bsum[b] = sd[0];
    if (t < 64) bhist[b * 64 + t] = hist[t];
}

__global__ __launch_bounds__(256) void csr_scan2(int* __restrict__ bsum,
                                                 const int* __restrict__ bhist, int* __restrict__ pbase) {
    __shared__ int sd[256];
    __shared__ int sg[64 * 4];
    __shared__ int base[64];
    int t = threadIdx.x;
    sd[t] = bsum[t];
    __syncthreads();
    for (int d = 1; d < 256; d <<= 1) {
        int v = (t >= d) ? sd[t - d] : 0;
        __syncthreads();
        if (t >= d) sd[t] += v;
        __syncthreads();
    }
    bsum[t] = (t > 0) ? sd[t - 1] : 0;

    int k = t & 63, g = t >> 6;
    int s = 0;
    for (int j = 0; j < 64; ++j) s += bhist[(g * 64 + j) * 64 + k];
    sg[k * 4 + g] = s;
    __syncthreads();
    if (t == 0) {
        int run = 0;
        for (int kk = 0; kk < 64; ++kk) {
            base[kk] = run;
            run += sg[kk * 4 + 0] + sg[kk * 4 + 1] + sg[kk * 4 + 2] + sg[kk * 4 + 3];
        }
    }
    __syncthreads();
    int run = base[k];
    for (int gg = 0; gg < g; ++gg) run += sg[k * 4 + gg];
    for (int j = 0; j < 64; ++j) {
        int b = g * 64 + j;
        pbase[b * 64 + k] = run;
        run += bhist[b * 64 + k];
    }
}

// exclusive scan of counts -> cursor, + desc[sorted_pos] = (node, beg, end, 0)
__global__ __launch_bounds__(256) void csr_scan3(const int* __restrict__ counts, const int* __restrict__ bsum,
                                                 int* __restrict__ cursor,
                                                 const int* __restrict__ pbase, int4* __restrict__ desc) {
    __shared__ int sd[256];
    __shared__ int cur[64];
    int t = threadIdx.x, b = blockIdx.x;
    if (t < 64) cur[t] = pbase[b * 64 + t];
    int idx = b * CHUNK + t;
    int v = (t < CHUNK && idx < N_NODES) ? counts[idx] : 0;
    sd[t] = v;
    __syncthreads();
    for (int d = 1; d < 256; d <<= 1) {
        int u = (t >= d) ? sd[t - d] : 0;
        __syncthreads();
        if (t >= d) sd[t] += u;
        __syncthreads();
    }
    if (t < CHUNK && idx < N_NODES) {
        int ex = bsum[b] + sd[t] - v;
        cursor[idx] = ex;
        int bin = 63 - min(v, 63);
        int p = atomicAdd(&cur[bin], 1);
        desc[p] = make_int4(idx, ex, ex + v, 0);
    }
}

// ---------------- MFMA GEMM: x8[node][1024B] fp8 e4m3 (xl cols 0..511, xr cols 512..1023) ----------------
// LDS-staged epilogue: 2x coalesced 16B stores per thread (was 8x 4B: store-issue-bound).
__global__ __launch_bounds__(256) void gemm_mfma(const ushort_t* __restrict__ xb,
                                                 const ushort_t* __restrict__ Wt,
                                                 uchar_t* __restrict__ x8,
                                                 const int* __restrict__ ei, int* __restrict__ cursor,
                                                 int* __restrict__ csr_src) {
    __shared__ ushort_t sW[128 * 72];    // 128 cols x 64 k, rows padded to 72 shorts (18 KB)
    __shared__ uchar_t sOut[64 * 144];   // 64 nodes x 128B results, rows padded to 144B (9 KB)
    int b = blockIdx.x;
    if (b >= GEMM_BLOCKS) {              // scatter part (layer-0 launch only)
        int t = (b - GEMM_BLOCKS) * 256 + threadIdx.x;
        if (t >= EP) return;
        int s, d; edge_sd(ei, t, s, d);
        int pos = atomicAdd(&cursor[d], 1);
        csr_src[pos] = s;
        return;
    }
    int colq = b / 782;
    int bx = b - colq * 782;
    int t = threadIdx.x;
    const ushort_t* Wg = Wt + (size_t)colq * 128 * 64;
    {
        int col = t >> 1, half = t & 1;
        const uint4* g = (const uint4*)(Wg + col * 64 + half * 32);
        uint4* l = (uint4*)(sW + col * 72 + half * 32);
        l[0] = g[0]; l[1] = g[1]; l[2] = g[2]; l[3] = g[3];
    }
    __syncthreads();
    int lane = t & 63, w = t >> 6;
    int ln = lane & 15, q = lane >> 4;
    int nl = w * 16 + ln;                // node_local 0..63
    int node = bx * 64 + nl;
    int nclamp = node < N_NODES ? node : N_NODES - 1;
    const short8 b0 = *(const short8*)(xb + (size_t)nclamp * 64 + q * 8);
    const short8 b1 = *(const short8*)(xb + (size_t)nclamp * 64 + 32 + q * 8);
#pragma unroll
    for (int ct = 0; ct < 8; ++ct) {
        const short8 a0 = *(const short8*)(sW + (ct * 16 + ln) * 72 + q * 8);
        const short8 a1 = *(const short8*)(sW + (ct * 16 + ln) * 72 + 32 + q * 8);
        f32x4 acc = {0.f, 0.f, 0.f, 0.f};
        acc = __builtin_amdgcn_mfma_f32_16x16x32_bf16(a0, b0, acc, 0, 0, 0);
        acc = __builtin_amdgcn_mfma_f32_16x16x32_bf16(a1, b1, acc, 0, 0, 0);
        int r = 0;
        r = __builtin_amdgcn_cvt_pk_fp8_f32(acc[0], acc[1], r, false);
        r = __builtin_amdgcn_cvt_pk_fp8_f32(acc[2], acc[3], r, true);
        *(uint_t*)(sOut + nl * 144 + ct * 16 + q * 4) = (uint_t)r;   // LDS deposit (2-way alias max)
    }
    __syncthreads();
#pragma unroll
    for (int k = 0; k < 2; ++k) {
        int c = t + k * 256;
        int nl2 = c >> 3, off = (c & 7) * 16;
        int node2 = bx * 64 + nl2;
        if (node2 < N_NODES) {
            uint4 v = *(const uint4*)(sOut + nl2 * 144 + off);
            *(uint4*)(x8 + (size_t)node2 * 1024 + colq * 128 + off) = v;
        }
    }
}

// ---------------- fused node kernel: fp8 gathers, bf16 residual from xb (in-place) ----------------
__global__ __launch_bounds__(256, 8) void node_fused(ushort_t* __restrict__ xb,      // in: residual, out: next-layer input
                                                  const uchar_t* __restrict__ x8,
                                                  const float* __restrict__ att,
                                                  const int4* __restrict__ desc, const int* __restrict__ csr_src,
                                                  const float* __restrict__ bias, const float* __restrict__ gamma,
                                                  const float* __restrict__ beta, float* __restrict__ x_out,
                                                  int write_out, int write_xb) {
    int4 dd = desc[blockIdx.x * 4 + (threadIdx.x >> 6)];
    int n   = __builtin_amdgcn_readfirstlane(dd.x);
    int beg = __builtin_amdgcn_readfirstlane(dd.y);
    int end = __builtin_amdgcn_readfirstlane(dd.z);
    int lane = threadIdx.x & 63;
    int h = lane >> 3, i = lane & 7;
    int off8 = h * 64 + i * 8;   // byte offset into 512B half-row

    // loop-invariants: xr (fp8), attention vector (fp32)
    uint2 ru = *(const uint2*)(x8 + (size_t)n * 1024 + 512 + off8);
    f32x2 rv0 = cvt8<false>(ru.x), rv1 = cvt8<true>(ru.x),
          rv2 = cvt8<false>(ru.y), rv3 = cvt8<true>(ru.y);
    const float4* pa = (const float4*)(att + h * 64 + i * 8);
    float4 aa = pa[0], ab = pa[1];
    f32x2 a0 = {aa.x, aa.y}, a1 = {aa.z, aa.w}, a2 = {ab.x, ab.y}, a3 = {ab.z, ab.w};
    f32x2 a60 = (0.6f * LOG2E) * a0, a61 = (0.6f * LOG2E) * a1,
          a62 = (0.6f * LOG2E) * a2, a63 = (0.6f * LOG2E) * a3;
    f32x2 a40 = (0.4f * LOG2E) * a0, a41 = (0.4f * LOG2E) * a1,
          a42 = (0.4f * LOG2E) * a2, a43 = (0.4f * LOG2E) * a3;

    float den = 0.f;
    f32x2 acc0 = {0.f, 0.f}, acc1 = {0.f, 0.f}, acc2 = {0.f, 0.f}, acc3 = {0.f, 0.f};

#define PROCESS(cur)                                                     \
    {                                                                    \
        f32x2 v0 = cvt8<false>(cur.x), v1 = cvt8<true>(cur.x),           \
              v2 = cvt8<false>(cur.y), v3 = cvt8<true>(cur.y);           \
        f32x2 p = pk_mul(a60, v0);                                       \
        p = pk_fma(a61, v1, p);                                          \
        p = pk_fma(a62, v2, p);                                          \
        p = pk_fma(a63, v3, p);                                          \
        p = pk_fma(a40, pk_abs(pk_add(v0, rv0)), p);                     \
        p = pk_fma(a41, pk_abs(pk_add(v1, rv1)), p);                     \
        p = pk_fma(a42, pk_abs(pk_add(v2, rv2)), p);                     \
        p = pk_fma(a43, pk_abs(pk_add(v3, rv3)), p);                     \
        float pdot = p.x + p.y;                                          \
        pdot += xor1_dpp(pdot);                                          \
        pdot += xor2_dpp(pdot);                                          \
        pdot += xor4_swz(pdot);                                          \
        float wgt = __builtin_exp2f(pdot);                               \
        den += wgt;                                                      \
        f32x2 wv = {wgt, wgt};                                           \
        acc0 = pk_fma(wv, v0, acc0);                                     \
        acc1 = pk_fma(wv, v1, acc1);                                     \
        acc2 = pk_fma(wv, v2, acc2);                                     \
        acc3 = pk_fma(wv, v3, acc3);                                     \
    }

    for (int base = beg; base < end; base += 64) {
        int idx = base + lane;
        int srcs = csr_src[idx < end ? idx : end - 1];   // coalesced batch load
        int cnt = min(64, end - base);
        int j = 0;
        for (; j + 8 <= cnt; j += 8) {
            uint2 q[8];
#pragma unroll
            for (int u = 0; u < 8; ++u) {
                int ss = __shfl(srcs, j + u);
                q[u] = *(const uint2*)(x8 + (size_t)ss * 1024 + off8);
            }
#pragma unroll
            for (int u = 0; u < 8; ++u) PROCESS(q[u]);
        }
        for (; j < cnt; ++j) {
            int ss = __shfl(srcs, j);
            uint2 qq = *(const uint2*)(x8 + (size_t)ss * 1024 + off8);
            PROCESS(qq);
        }
    }
#undef PROCESS

    // normalize per head (0.125 head-mean folded in), reduce over heads (xor 8,16,32)
    float invden = 0.125f / den;
    f32x2 iv = {invden, invden};
    acc0 = pk_mul(acc0, iv); acc1 = pk_mul(acc1, iv);
    acc2 = pk_mul(acc2, iv); acc3 = pk_mul(acc3, iv);
    float acc[8] = {acc0.x, acc0.y, acc1.x, acc1.y, acc2.x, acc2.y, acc3.x, acc3.y};
#pragma unroll
    for (int k2 = 0; k2 < 8; ++k2) {
        acc[k2] += xor8_dpp(acc[k2]);
        acc[k2] += xor16_swz(acc[k2]);
        acc[k2] += __shfl_xor(acc[k2], 32);
    }

    // bias + residual (bf16 xb); LN stats across channels
    int cbase = i * 8;
    uint4 pxu = *(const uint4*)(xb + (size_t)n * 64 + cbase);
    f32x2 x01 = mkf2(pxu.x), x23 = mkf2(pxu.y), x45 = mkf2(pxu.z), x67 = mkf2(pxu.w);
    float xi[8] = {x01.x, x01.y, x23.x, x23.y, x45.x, x45.y, x67.x, x67.y};
    float v[8];
    float sum = 0.f, sq = 0.f;
#pragma unroll
    for (int k2 = 0; k2 < 8; ++k2) {
        float val = acc[k2] + bias[cbase + k2] + xi[k2];
        v[k2] = val; sum += val; sq += val * val;
    }
    sum += xor1_dpp(sum); sq += xor1_dpp(sq);
    sum += xor2_dpp(sum); sq += xor2_dpp(sq);
    sum += xor4_swz(sum); sq += xor4_swz(sq);
    float mu   = sum * (1.0f / 64.0f);
    float var  = sq * (1.0f / 64.0f) - mu * mu;
    float rstd = rsqrtf(var + LN_EPS);

    if (h == 0) {
        float o[8];
#pragma unroll
        for (int k2 = 0; k2 < 8; ++k2) {
            float y = (v[k2] - mu) * rstd * gamma[cbase + k2] + beta[cbase + k2];
            o[k2] = fmaxf(y, 0.f);
        }
        if (write_out) {
            float4* po = (float4*)(x_out + n * 64 + cbase);
            po[0] = make_float4(o[0], o[1], o[2], o[3]);
            po[1] = make_float4(o[4], o[5], o[6], o[7]);
        }
        if (write_xb) {
            *(uint4*)(xb + (size_t)n * 64 + cbase) =
                make_uint4(pack_bf2(o[0], o[1]), pack_bf2(o[2], o[3]),
                           pack_bf2(o[4], o[5]), pack_bf2(o[6], o[7]));
        }
    }
}

// ---------------- host ----------------

extern "C" void kernel_launch(void* const* d_in, const int* in_sizes, int n_in,
                              void* d_out, int out_size, void* d_ws, size_t ws_size,
                              hipStream_t stream) {
    const float* x     = (const float*)d_in[0];
    const float* Wl    = (const float*)d_in[1];
    const float* Wr    = (const float*)d_in[2];
    const float* att   = (const float*)d_in[3];
    const float* b     = (const float*)d_in[4];
    const float* gamma = (const float*)d_in[5];
    const float* beta  = (const float*)d_in[6];
    const int*   ei    = (const int*)d_in[7];
    float* out = (float*)d_out;

    uchar_t* x8    = (uchar_t*)d_ws;                         // PAD_N*1024 fp8 (xl | xr)
    ushort_t* xb   = (ushort_t*)(x8 + (size_t)PAD_N * 1024); // PAD_N*64 bf16 (layer input / residual)
    ushort_t* Wt   = xb + (size_t)PAD_N * 64;                // 3*1024*64 bf16
    int* counts    = (int*)(Wt + 3 * 1024 * 64);             // PAD_N
    int* cursor    = counts + PAD_N;                         // PAD_N
    int* bsum      = cursor + PAD_N;                         // 256
    int* bhist     = bsum + 256;                             // 256*64
    int* pbase     = bhist + SCAN_BLOCKS * 64;               // 256*64
    int4* desc     = (int4*)(pbase + SCAN_BLOCKS * 64);      // PAD_N int4
    int* csr_src   = (int*)(desc + PAD_N);                   // EP

    hipMemsetAsync(counts, 0, N_NODES * sizeof(int), stream);

    // wide setup: histogram + x/W bf16 conversion in one launch
    int setup_threads = EP + N_NODES * 64 + 3 * 1024 * 64;
    setup_all<<<(setup_threads + 255) / 256, 256, 0, stream>>>(ei, counts, x, Wl, Wr, xb, Wt);

    csr_scan1<<<SCAN_BLOCKS, 256, 0, stream>>>(counts, bsum, bhist);
    csr_scan2<<<1, 256, 0, stream>>>(bsum, bhist, pbase);
    csr_scan3<<<SCAN_BLOCKS, 256, 0, stream>>>(counts, bsum, cursor, pbase, desc);

    int eb = (EP + 255) / 256;
    for (int l = 0; l < 3; ++l) {
        int grid = (l == 0) ? GEMM_BLOCKS + eb : GEMM_BLOCKS;   // layer 0 also scatters CSR
        gemm_mfma <<<grid, 256, 0, stream>>>(xb, Wt + (size_t)l * 1024 * 64, x8, ei, cursor, csr_src);
        node_fused<<<N_NODES / 4, 256, 0, stream>>>(xb, x8, att + l * (H * D), desc, csr_src,
                                                    b + l * D, gamma + l * D, beta + l * D,
                                                    out, (l == 2) ? 1 : 0, (l < 2) ? 1 : 0);
    }
}